// Round 5
// baseline (533.661 us; speedup 1.0000x reference)
//
#include <hip/hip_runtime.h>
#include <math.h>

#define H 1024
#define V 18
#define NUM_NODES 7
#define LEN 40
#define BATCH 512
#define NWG 256
#define NT 1024

#define AGENT __HIP_MEMORY_SCOPE_AGENT
typedef unsigned long long u64;

// ws layout:
//   u64 h1s[2][1024]   (16 KB)  packed (tag<<32)|float
//   u64 h2s[2][1024]   (16 KB)
//   f32 c1buf[1024]    (4 KB)
//   f32 c2buf[1024]    (4 KB)
#define WS_ZERO_U32 (4096 + 4096 + 1024 + 1024)

__device__ __forceinline__ float wred(float v) {
#pragma unroll
  for (int off = 32; off > 0; off >>= 1) v += __shfl_xor(v, off, 64);
  return v;
}
__device__ __forceinline__ float sigm(float x) { return 1.0f / (1.0f + expf(-x)); }
__device__ __forceinline__ float dot4(float4 a, float4 b) {
  return a.x * b.x + a.y * b.y + a.z * b.z + a.w * b.w;
}
// opaque pin: value becomes asm-defined; compiler cannot rematerialize it
#define OPQ4(v) asm volatile("v_mov_b32 %0, %0\n\tv_mov_b32 %1, %1\n\tv_mov_b32 %2, %2\n\tv_mov_b32 %3, %3" \
                             : "+v"(v.x), "+v"(v.y), "+v"(v.z), "+v"(v.w))

__device__ __forceinline__ void pub(u64* slot, unsigned tag, float v) {
  u64 x = ((u64)tag << 32) | (u64)__float_as_uint(v);
  __hip_atomic_store(slot, x, __ATOMIC_RELAXED, AGENT);
}
__device__ __forceinline__ float poll_slot(u64* slot, unsigned tag) {
  u64 x;
  for (;;) {
    x = __hip_atomic_load(slot, __ATOMIC_RELAXED, AGENT);
    if ((unsigned)(x >> 32) == tag) break;
    __builtin_amdgcn_s_sleep(1);
  }
  return __uint_as_float((unsigned)x);
}

__global__ void __launch_bounds__(256) init_ws_kernel(unsigned* p, int n) {
  int i = blockIdx.x * 256 + threadIdx.x;
  if (i < n) p[i] = 0u;
}

__global__ void __launch_bounds__(NT, 4) decoder_kernel(
    const int* __restrict__ x0,
    const float* __restrict__ emb,    // [V][H]
    const float* __restrict__ w_ih,   // [L][4H][H]
    const float* __restrict__ w_hh,   // [L][4H][H]
    const float* __restrict__ b_ih,   // [L][4H]
    const float* __restrict__ b_hh,   // [L][4H]
    const float* __restrict__ w_fc,   // [V][H]
    const float* __restrict__ b_fc,   // [V]
    float* __restrict__ out,
    float* __restrict__ ws)
{
  u64* h1s = (u64*)ws;
  u64* h2s = h1s + 2 * H;
  float* c1buf = (float*)(h2s + 2 * H);
  float* c2buf = c1buf + H;

  float* out_tok  = out;                           // [LEN][BATCH] (as float)
  float* out_outs = out + LEN * BATCH;             // [BATCH][V]
  float* out_hf   = out_outs + BATCH * V;          // [2][BATCH][H]
  float* out_cf   = out_hf + 2 * BATCH * H;        // [2][BATCH][H]

  const int wg = blockIdx.x, tid = threadIdx.x;
  const int wave = tid >> 6, lane = tid & 63;
  const int q = wave & 3;          // gate (i,f,g,o)
  const int u = wave >> 2;         // unit-within-WG (0..3)
  const int row = q * H + (wg * 4 + u);  // gate row within a layer

  // ---- loop-resident weights, opaque-pinned in VGPRs (64 regs) ----
  float4 wh0[4], wi1[4], wh1[4], wfc[4];
  {
    const float4* p1 = (const float4*)(w_hh + (size_t)row * H);
    const float4* p2 = (const float4*)(w_ih + (size_t)(4 * H + row) * H);
    const float4* p3 = (const float4*)(w_hh + (size_t)(4 * H + row) * H);
    const float4* p4 = (const float4*)(w_fc + (size_t)(wave & 15) * H);
#pragma unroll
    for (int m = 0; m < 4; ++m) {
      wh0[m] = p1[lane + 64 * m];
      wi1[m] = p2[lane + 64 * m];
      wh1[m] = p3[lane + 64 * m];
      wfc[m] = p4[lane + 64 * m];
      OPQ4(wh0[m]); OPQ4(wi1[m]); OPQ4(wh1[m]); OPQ4(wfc[m]);
    }
  }
  const float bsum1 = b_ih[4 * H + row] + b_hh[4 * H + row];
  const float bfc_w = b_fc[wave & 15];
  const float bfc_2 = (wave >= 14) ? b_fc[wave + 2] : 0.f;  // v = 16,17 on waves 14,15

  __shared__ __align__(16) float s_h1[H];
  __shared__ __align__(16) float s_h2[H];
  __shared__ float s_eix[16][V];    // eix[wave][v] = wi0_row . emb[v] + bias0
  __shared__ float s_g1[4][4];
  __shared__ float s_g2[4][4];
  __shared__ float s_logits[V];
  __shared__ int s_tok;
  __shared__ float s_lse;

  // ---- prologue: fold wi0 . emb[v] for all 18 tokens (emb constant) ----
  {
    float4 wi0[4];
    const float4* p0p = (const float4*)(w_ih + (size_t)row * H);
#pragma unroll
    for (int m = 0; m < 4; ++m) wi0[m] = p0p[lane + 64 * m];
    const float bsum0 = b_ih[row] + b_hh[row];
    for (int v = 0; v < V; ++v) {
      const float4* er = (const float4*)(emb + (size_t)v * H);
      float a = 0.f;
#pragma unroll
      for (int m = 0; m < 4; ++m) a += dot4(wi0[m], er[lane + 64 * m]);
      a = wred(a);
      if (lane == 0) s_eix[wave][v] = a + bsum0;
    }
  }
  s_h1[tid] = 0.f;
  s_h2[tid] = 0.f;
  __syncthreads();

  int tok = x0[0];
  float p0 = 0.f;            // partial wh0 . h1(t-1)
  float c1 = 0.f, c2 = 0.f;  // cell states (wave0 lanes 0..3)

  for (int t = 0; t < LEN; ++t) {
    const int pw = t & 1;
    const unsigned tag = (unsigned)(t + 1);

    // ---- Phase A: layer-0 gates = eix[tok] + p0 (p0 precomputed) ----
    {
      float g0 = wred(p0);
      if (lane == 0) s_g1[u][q] = g0 + s_eix[wave][tok];
    }
    __syncthreads();
    if (wave == 0 && lane < 4) {
      const int jj = wg * 4 + lane;
      float ig = sigm(s_g1[lane][0]), fg = sigm(s_g1[lane][1]);
      float gg = tanhf(s_g1[lane][2]), og = sigm(s_g1[lane][3]);
      c1 = fg * c1 + ig * gg;
      float hn = og * tanhf(c1);
      if (t == LEN - 1) {
        __hip_atomic_store(&c1buf[jj], c1, __ATOMIC_RELAXED, AGENT);
        asm volatile("s_waitcnt vmcnt(0)" ::: "memory");
      }
      pub(&h1s[pw * H + jj], tag, hn);   // value+tag in ONE 8B store
    }
    // overlap h1 wait: partial wh1 . h2(t-1)
    float p1 = 0.f;
#pragma unroll
    for (int m = 0; m < 4; ++m)
      p1 += dot4(wh1[m], ((const float4*)s_h2)[lane + 64 * m]);
    // dataflow sync: each thread polls its own h1 slot
    {
      float v = poll_slot(&h1s[pw * H + tid], tag);
      s_h1[tid] = v;
    }
    __syncthreads();

    // ---- Phase B: layer-1 gates = p1 + wi1 . h1(t) ----
    {
      float a = p1;
#pragma unroll
      for (int m = 0; m < 4; ++m)
        a += dot4(wi1[m], ((const float4*)s_h1)[lane + 64 * m]);
      a = wred(a);
      if (lane == 0) s_g2[u][q] = a + bsum1;
    }
    __syncthreads();
    if (wave == 0 && lane < 4) {
      const int jj = wg * 4 + lane;
      float ig = sigm(s_g2[lane][0]), fg = sigm(s_g2[lane][1]);
      float gg = tanhf(s_g2[lane][2]), og = sigm(s_g2[lane][3]);
      c2 = fg * c2 + ig * gg;
      float hn = og * tanhf(c2);
      if (t == LEN - 1) {
        __hip_atomic_store(&c2buf[jj], c2, __ATOMIC_RELAXED, AGENT);
        asm volatile("s_waitcnt vmcnt(0)" ::: "memory");
      }
      pub(&h2s[pw * H + jj], tag, hn);
    }
    // early-issue the two extra fc rows (v=16,17) while h2 is in flight
    float4 wfc2[4];
    if (wave >= 14) {
      const float4* pf2 = (const float4*)(w_fc + (size_t)(wave + 2) * H);
#pragma unroll
      for (int m = 0; m < 4; ++m) wfc2[m] = pf2[lane + 64 * m];
    }
    // overlap h2 wait: next step's partial wh0 . h1(t)
    float p0n = 0.f;
#pragma unroll
    for (int m = 0; m < 4; ++m)
      p0n += dot4(wh0[m], ((const float4*)s_h1)[lane + 64 * m]);
    {
      float v = poll_slot(&h2s[pw * H + tid], tag);
      s_h2[tid] = v;
    }
    __syncthreads();
    p0 = p0n;

    // ---- Phase C: fc + argmax (redundant per WG, no grid sync) ----
    {
      {
        float a = 0.f;
#pragma unroll
        for (int m = 0; m < 4; ++m)
          a += dot4(wfc[m], ((const float4*)s_h2)[lane + 64 * m]);
        a = wred(a);
        if (lane == 0) s_logits[wave] = a + bfc_w;
      }
      if (wave >= 14) {
        float a = 0.f;
#pragma unroll
        for (int m = 0; m < 4; ++m)
          a += dot4(wfc2[m], ((const float4*)s_h2)[lane + 64 * m]);
        a = wred(a);
        if (lane == 0) s_logits[wave + 2] = a + bfc_2;
      }
      __syncthreads();
      if (tid == 0) {
        const int node_end = ((t >> 1) % 10) / 2 + 3;
        float bv = -INFINITY;
        int bi = 0;
        for (int v = 0; v < V; ++v) {
          bool m = (t & 1) ? (v >= NUM_NODES) : (v >= 1 && v < node_end);
          if (m && s_logits[v] > bv) { bv = s_logits[v]; bi = v; }
        }
        s_tok = bi;
      }
      __syncthreads();
      tok = s_tok;

      if (wg == 0) {
        if (tid >= 512) out_tok[t * BATCH + (tid - 512)] = (float)tok;
        if (t == LEN - 1) {
          if (tid == 0) {
            float mx = -INFINITY;
            for (int v = 0; v < V; ++v) mx = fmaxf(mx, s_logits[v]);
            float s = 0.f;
            for (int v = 0; v < V; ++v) s += expf(s_logits[v] - mx);
            s_lse = mx + logf(s);
          }
          __syncthreads();
          for (int i = tid; i < BATCH * V; i += NT)
            out_outs[i] = s_logits[i % V] - s_lse;
        }
      }
    }
  }

  // ---- Final: broadcast h_f, c_f (s_h1/s_h2 hold h(39); c published) ----
  for (int z = tid; z < 4 * (H / 4); z += NT) {
    const int rr = z >> 8;          // 0..3
    const int i  = z & 255;         // float4 index within row
    const int r  = wg + rr * NWG;   // row in [0, 1024)
    const float* hsrc = (r >> 9) == 0 ? s_h1 : s_h2;
    ((float4*)(out_hf + (size_t)r * H))[i] = ((const float4*)hsrc)[i];
  }
  __syncthreads();
  s_h1[tid] = __hip_atomic_load(&c1buf[tid], __ATOMIC_RELAXED, AGENT);
  s_h2[tid] = __hip_atomic_load(&c2buf[tid], __ATOMIC_RELAXED, AGENT);
  __syncthreads();
  for (int z = tid; z < 4 * (H / 4); z += NT) {
    const int rr = z >> 8;
    const int i  = z & 255;
    const int r  = wg + rr * NWG;
    const float* csrc = (r >> 9) == 0 ? s_h1 : s_h2;
    ((float4*)(out_cf + (size_t)r * H))[i] = ((const float4*)csrc)[i];
  }
}

extern "C" void kernel_launch(void* const* d_in, const int* in_sizes, int n_in,
                              void* d_out, int out_size, void* d_ws, size_t ws_size,
                              hipStream_t stream) {
  const int*   x0   = (const int*)d_in[0];
  const float* emb  = (const float*)d_in[1];
  const float* w_ih = (const float*)d_in[2];
  const float* w_hh = (const float*)d_in[3];
  const float* b_ih = (const float*)d_in[4];
  const float* b_hh = (const float*)d_in[5];
  const float* w_fc = (const float*)d_in[6];
  const float* b_fc = (const float*)d_in[7];
  float* ws = (float*)d_ws;

  hipLaunchKernelGGL(init_ws_kernel, dim3((WS_ZERO_U32 + 255) / 256), dim3(256), 0, stream,
                     (unsigned*)ws, WS_ZERO_U32);
  hipLaunchKernelGGL(decoder_kernel, dim3(NWG), dim3(NT), 0, stream,
                     x0, emb, w_ih, w_hh, b_ih, b_hh, w_fc, b_fc,
                     (float*)d_out, ws);
}

// Round 6
// 400.027 us; speedup vs baseline: 1.3341x; 1.3341x over previous
//
#include <hip/hip_runtime.h>
#include <hip/hip_fp16.h>
#include <math.h>

#define H 1024
#define V 18
#define NUM_NODES 7
#define LEN 40
#define BATCH 512
#define NWG 256
#define NT 1024

#define AGENT __HIP_MEMORY_SCOPE_AGENT
typedef unsigned long long u64;
typedef _Float16 half2v __attribute__((ext_vector_type(2)));

// ws layout:
//   u64 h1s[2][1024]   packed (tag<<32)|float_bits
//   u64 h2s[2][1024]
//   f32 c1buf[1024], c2buf[1024]
#define WS_ZERO_U32 (4096 + 4096 + 1024 + 1024)

__device__ __forceinline__ float wred(float v) {
#pragma unroll
  for (int off = 32; off > 0; off >>= 1) v += __shfl_xor(v, off, 64);
  return v;
}
__device__ __forceinline__ float sigm(float x) { return 1.0f / (1.0f + expf(-x)); }
__device__ __forceinline__ float dot4(float4 a, float4 b) {
  return a.x * b.x + a.y * b.y + a.z * b.z + a.w * b.w;
}

__device__ __forceinline__ float fdot2_(unsigned w, unsigned h, float c) {
  half2v a = __builtin_bit_cast(half2v, w);
  half2v b = __builtin_bit_cast(half2v, h);
#if __has_builtin(__builtin_amdgcn_fdot2)
  return __builtin_amdgcn_fdot2(a, b, c, false);
#else
  return c + (float)a.x * (float)b.x + (float)a.y * (float)b.y;
#endif
}

// dot of one 1024-elem f16 row (LDS) with f16 h vector (LDS), fp32 accum.
// Layout: natural half2-pair order; lane reads uint2 at 8*lane + 512*k -> 2-way bank (free).
__device__ __forceinline__ float dot_row(const unsigned* wrow, const unsigned* hp, int lane) {
  float a = 0.f;
#pragma unroll
  for (int k = 0; k < 4; ++k) {
    uint2 w = *(const uint2*)(wrow + 2 * lane + 128 * k);
    uint2 h = *(const uint2*)(hp + 2 * lane + 128 * k);
    a = fdot2_(w.x, h.x, a);
    a = fdot2_(w.y, h.y, a);
  }
  return a;
}

__device__ __forceinline__ void pub(u64* slot, unsigned tag, float v) {
  u64 x = ((u64)tag << 32) | (u64)__float_as_uint(v);
  __hip_atomic_store(slot, x, __ATOMIC_RELAXED, AGENT);
}
__device__ __forceinline__ float poll_slot(u64* slot, unsigned tag) {
  u64 x;
  for (;;) {
    x = __hip_atomic_load(slot, __ATOMIC_RELAXED, AGENT);
    if ((unsigned)(x >> 32) == tag) break;
    __builtin_amdgcn_s_sleep(1);
  }
  return __uint_as_float((unsigned)x);
}

__global__ void __launch_bounds__(256) init_ws_kernel(unsigned* p, int n) {
  int i = blockIdx.x * 256 + threadIdx.x;
  if (i < n) p[i] = 0u;
}

__global__ void __launch_bounds__(NT, 4) decoder_kernel(
    const int* __restrict__ x0,
    const float* __restrict__ emb,    // [V][H]
    const float* __restrict__ w_ih,   // [L][4H][H]
    const float* __restrict__ w_hh,   // [L][4H][H]
    const float* __restrict__ b_ih,   // [L][4H]
    const float* __restrict__ b_hh,   // [L][4H]
    const float* __restrict__ w_fc,   // [V][H]
    const float* __restrict__ b_fc,   // [V]
    float* __restrict__ out,
    float* __restrict__ ws)
{
  u64* h1s = (u64*)ws;
  u64* h2s = h1s + 2 * H;
  float* c1buf = (float*)(h2s + 2 * H);
  float* c2buf = c1buf + H;

  float* out_tok  = out;                           // [LEN][BATCH] (as float)
  float* out_outs = out + LEN * BATCH;             // [BATCH][V]
  float* out_hf   = out_outs + BATCH * V;          // [2][BATCH][H]
  float* out_cf   = out_hf + 2 * BATCH * H;        // [2][BATCH][H]

  const int wg = blockIdx.x, tid = threadIdx.x;
  const int wave = tid >> 6, lane = tid & 63;
  const int q = wave & 3;                // gate (i,f,g,o)
  const int u = wave >> 2;               // unit-within-WG (0..3)
  const int row = q * H + (wg * 4 + u);  // gate row within a layer

  // ---- LDS-resident f16 weights ----
  // slots: 0..15 wh0[wave], 16..31 wi1[wave], 32..47 wh1[wave], 48..65 wfc[v]
  __shared__ unsigned wlds[66][512];       // 132 KB
  __shared__ unsigned h1p[512], h2p[512];  // f16-packed h vectors
  __shared__ float s_eix[16][V];
  __shared__ float s_g1[4][4], s_g2[4][4];
  __shared__ float s_logits[V];
  __shared__ float s_bfc[V];
  __shared__ int   s_tok;
  __shared__ float s_lse;

  // ---- prologue 1: stage weights (fp32 global -> f16 LDS) ----
  for (int i = tid; i < 66 * 512; i += NT) {
    const int slot = i >> 9, p = i & 511;
    const float* src;
    if (slot < 16) {
      src = w_hh + (size_t)((slot & 3) * H + wg * 4 + (slot >> 2)) * H;
    } else if (slot < 32) {
      const int s = slot - 16;
      src = w_ih + (size_t)(4 * H + (s & 3) * H + wg * 4 + (s >> 2)) * H;
    } else if (slot < 48) {
      const int s = slot - 32;
      src = w_hh + (size_t)(4 * H + (s & 3) * H + wg * 4 + (s >> 2)) * H;
    } else {
      src = w_fc + (size_t)(slot - 48) * H;
    }
    float2 f = *(const float2*)(src + 2 * p);
    __half2 hh = __floats2half2_rn(f.x, f.y);
    wlds[slot][p] = *(unsigned*)&hh;
  }
  if (tid < V) s_bfc[tid] = b_fc[tid];
  if (tid < 512) { h1p[tid] = 0u; h2p[tid] = 0u; }

  // ---- prologue 2: eix[wave][v] = wi0_row . emb[v] + b0 (fp32, emb const) ----
  {
    float4 wi0[4];
    const float4* p0p = (const float4*)(w_ih + (size_t)row * H);
#pragma unroll
    for (int m = 0; m < 4; ++m) wi0[m] = p0p[lane + 64 * m];
    const float bsum0 = b_ih[row] + b_hh[row];
    for (int v = 0; v < V; ++v) {
      const float4* er = (const float4*)(emb + (size_t)v * H);
      float a = 0.f;
#pragma unroll
      for (int m = 0; m < 4; ++m) a += dot4(wi0[m], er[lane + 64 * m]);
      a = wred(a);
      if (lane == 0) s_eix[wave][v] = a + bsum0;
    }
  }
  const float bsum1 = b_ih[4 * H + row] + b_hh[4 * H + row];
  __syncthreads();

  int tok = x0[0];
  float p0 = 0.f;            // wh0 . h1(t-1), precomputed previous step
  float c1 = 0.f, c2 = 0.f;  // cell states (wave0 lanes 0..3)

  for (int t = 0; t < LEN; ++t) {
    const int pw = t & 1;
    const unsigned tag = (unsigned)(t + 1);

    // ---- Phase A: layer-0 gates = eix[tok] + p0 ----
    {
      float g0 = wred(p0);
      if (lane == 0) s_g1[u][q] = g0 + s_eix[wave][tok];
    }
    __syncthreads();
    if (wave == 0 && lane < 4) {
      const int jj = wg * 4 + lane;
      float ig = sigm(s_g1[lane][0]), fg = sigm(s_g1[lane][1]);
      float gg = tanhf(s_g1[lane][2]), og = sigm(s_g1[lane][3]);
      c1 = fg * c1 + ig * gg;
      float hn = og * tanhf(c1);
      if (t == LEN - 1) {
        __hip_atomic_store(&c1buf[jj], c1, __ATOMIC_RELAXED, AGENT);
        asm volatile("s_waitcnt vmcnt(0)" ::: "memory");
      }
      pub(&h1s[pw * H + jj], tag, hn);
    }
    // overlap: wh1 . h2(t-1) while h1 is in flight
    float p1 = dot_row(wlds[32 + wave], h2p, lane);
    {
      float v = poll_slot(&h1s[pw * H + tid], tag);
      float vn = __shfl_down(v, 1);
      if ((tid & 1) == 0) {
        __half2 hh = __floats2half2_rn(v, vn);
        h1p[tid >> 1] = *(unsigned*)&hh;
      }
    }
    __syncthreads();

    // ---- Phase B: layer-1 gates = p1 + wi1 . h1(t) ----
    {
      float a = p1 + dot_row(wlds[16 + wave], h1p, lane);
      a = wred(a);
      if (lane == 0) s_g2[u][q] = a + bsum1;
    }
    __syncthreads();
    if (wave == 0 && lane < 4) {
      const int jj = wg * 4 + lane;
      float ig = sigm(s_g2[lane][0]), fg = sigm(s_g2[lane][1]);
      float gg = tanhf(s_g2[lane][2]), og = sigm(s_g2[lane][3]);
      c2 = fg * c2 + ig * gg;
      float hn = og * tanhf(c2);
      if (t == LEN - 1) {
        __hip_atomic_store(&c2buf[jj], c2, __ATOMIC_RELAXED, AGENT);
        asm volatile("s_waitcnt vmcnt(0)" ::: "memory");
      }
      pub(&h2s[pw * H + jj], tag, hn);
    }
    // overlap: next step's wh0 . h1(t) while h2 is in flight
    float p0n = dot_row(wlds[wave], h1p, lane);
    {
      float v = poll_slot(&h2s[pw * H + tid], tag);
      float vn = __shfl_down(v, 1);
      if ((tid & 1) == 0) {
        __half2 hh = __floats2half2_rn(v, vn);
        h2p[tid >> 1] = *(unsigned*)&hh;
      }
    }
    __syncthreads();
    p0 = p0n;

    // ---- Phase C: fc + argmax (redundant per WG, local only) ----
    {
      {
        float a = dot_row(wlds[48 + wave], h2p, lane);
        a = wred(a);
        if (lane == 0) s_logits[wave] = a + s_bfc[wave];
      }
      if (wave >= 14) {  // waves 14,15 also cover v = 16,17
        float a = dot_row(wlds[48 + wave + 2], h2p, lane);
        a = wred(a);
        if (lane == 0) s_logits[wave + 2] = a + s_bfc[wave + 2];
      }
      __syncthreads();
      if (tid == 0) {
        const int node_end = ((t >> 1) % 10) / 2 + 3;
        float bv = -INFINITY;
        int bi = 0;
        for (int v = 0; v < V; ++v) {
          bool m = (t & 1) ? (v >= NUM_NODES) : (v >= 1 && v < node_end);
          if (m && s_logits[v] > bv) { bv = s_logits[v]; bi = v; }
        }
        s_tok = bi;
      }
      __syncthreads();
      tok = s_tok;

      if (wg == 0) {
        if (tid < BATCH) out_tok[t * BATCH + tid] = (float)tok;
        if (t == LEN - 1) {
          if (tid == 0) {
            float mx = -INFINITY;
            for (int v = 0; v < V; ++v) mx = fmaxf(mx, s_logits[v]);
            float s = 0.f;
            for (int v = 0; v < V; ++v) s += expf(s_logits[v] - mx);
            s_lse = mx + logf(s);
          }
          __syncthreads();
          for (int i = tid; i < BATCH * V; i += NT)
            out_outs[i] = s_logits[i % V] - s_lse;
        }
      }
    }
  }

  // ---- Final outputs: h_f from f16 staged vectors, c_f from global slots ----
  {
    const unsigned u1 = h1p[tid >> 1], u2 = h2p[tid >> 1];
    const half2v v1 = __builtin_bit_cast(half2v, u1);
    const half2v v2 = __builtin_bit_cast(half2v, u2);
    const float h1v = (float)((tid & 1) ? v1.y : v1.x);
    const float h2v = (float)((tid & 1) ? v2.y : v2.x);
    const float cv1 = __hip_atomic_load(&c1buf[tid], __ATOMIC_RELAXED, AGENT);
    const float cv2 = __hip_atomic_load(&c2buf[tid], __ATOMIC_RELAXED, AGENT);
#pragma unroll
    for (int rr = 0; rr < 4; ++rr) {
      const int r = wg + rr * NWG;      // row in [0, 1024)
      const int l = r >> 9;             // layer
      out_hf[(size_t)r * H + tid] = l ? h2v : h1v;
      out_cf[(size_t)r * H + tid] = l ? cv2 : cv1;
    }
  }
}

extern "C" void kernel_launch(void* const* d_in, const int* in_sizes, int n_in,
                              void* d_out, int out_size, void* d_ws, size_t ws_size,
                              hipStream_t stream) {
  const int*   x0   = (const int*)d_in[0];
  const float* emb  = (const float*)d_in[1];
  const float* w_ih = (const float*)d_in[2];
  const float* w_hh = (const float*)d_in[3];
  const float* b_ih = (const float*)d_in[4];
  const float* b_hh = (const float*)d_in[5];
  const float* w_fc = (const float*)d_in[6];
  const float* b_fc = (const float*)d_in[7];
  float* ws = (float*)d_ws;

  hipLaunchKernelGGL(init_ws_kernel, dim3((WS_ZERO_U32 + 255) / 256), dim3(256), 0, stream,
                     (unsigned*)ws, WS_ZERO_U32);
  hipLaunchKernelGGL(decoder_kernel, dim3(NWG), dim3(NT), 0, stream,
                     x0, emb, w_ih, w_hh, b_ih, b_hh, w_fc, b_fc,
                     (float*)d_out, ws);
}